// Round 2
// baseline (96.644 us; speedup 1.0000x reference)
//
#include <hip/hip_runtime.h>
#include <math.h>

#define DIMS 3
#define NPTS 320
#define HID  128
#define RANK 64

typedef __attribute__((ext_vector_type(8))) short  bf16x8;
typedef __attribute__((ext_vector_type(4))) float  f32x4;

// round-to-nearest-even float -> bf16 bits
static __device__ __forceinline__ unsigned short f2bf_rn(float x) {
    union { float f; unsigned int u; } v; v.f = x;
    unsigned int r = v.u + 0x7fffu + ((v.u >> 16) & 1u);
    return (unsigned short)(r >> 16);
}
static __device__ __forceinline__ float bf2f(unsigned short h) {
    union { unsigned int u; float f; } v; v.u = ((unsigned int)h) << 16;
    return v.f;
}

// ---------------- Phase 1: per-dim MLP -> transposed factor tables ----------
// f0t[a][r], f1t[b][r] fp32 in f01t[2][NPTS][RANK];
// f2t split to bf16 hi/lo: f2hi[c][r], f2lo[c][r].
__global__ __launch_bounds__(HID)
void mlp_kernel(const float* __restrict__ xs,
                const float* __restrict__ W0, const float* __restrict__ b0,
                const float* __restrict__ W1, const float* __restrict__ b1,
                const float* __restrict__ W2, const float* __restrict__ b2,
                const float* __restrict__ W3, const float* __restrict__ b3,
                float* __restrict__ f01t,
                unsigned short* __restrict__ f2hi,
                unsigned short* __restrict__ f2lo) {
    int blk = blockIdx.x;
    int d = blk / NPTS, n = blk % NPTS;
    int j = threadIdx.x;

    __shared__ float ha[HID];
    __shared__ float hb[HID];

    float x = xs[d * NPTS + n];

    ha[j] = tanhf(fmaf(x, W0[d * HID + j], b0[d * HID + j]));
    __syncthreads();

    {
        float acc = b1[d * HID + j];
        const float* w = W1 + d * HID * HID + j;
        #pragma unroll 8
        for (int k = 0; k < HID; ++k) acc = fmaf(ha[k], w[k * HID], acc);
        hb[j] = tanhf(acc);
    }
    __syncthreads();

    {
        float acc = b2[d * HID + j];
        const float* w = W2 + d * HID * HID + j;
        #pragma unroll 8
        for (int k = 0; k < HID; ++k) acc = fmaf(hb[k], w[k * HID], acc);
        ha[j] = tanhf(acc);
    }
    __syncthreads();

    if (j < RANK) {
        float acc = b3[d * RANK + j];
        const float* w = W3 + d * HID * RANK + j;
        #pragma unroll 8
        for (int k = 0; k < HID; ++k) acc = fmaf(ha[k], w[k * RANK], acc);

        if (d == 0) {
            f01t[n * RANK + j] = acc;                    // f0t[a][r]
        } else if (d == 1) {
            f01t[(NPTS + n) * RANK + j] = acc;           // f1t[b][r]
        } else {
            unsigned short hi = f2bf_rn(acc);
            f2hi[n * RANK + j] = hi;
            f2lo[n * RANK + j] = f2bf_rn(acc - bf2f(hi));
        }
    }
}

// ---------------- Phase 2: CP reconstruction via bf16 MFMA (hi/lo split) ----
// out[a,b,c] = sum_r (f0[a,r]*f1[b,r]) * f2[c,r]
// Block: one a, 64-wide b tile (4 waves x 16 rows), full c=320 (20 tiles).
// A frag generated in-register (g = f0*f1, split hi/lo bf16); B frags are
// contiguous bf16x8 loads from f2hi/f2lo. No LDS tiles, no inner barriers.
__global__ __launch_bounds__(256)
void cp_mfma_kernel(const float* __restrict__ f01t,
                    const unsigned short* __restrict__ f2hi,
                    const unsigned short* __restrict__ f2lo,
                    float* __restrict__ out) {
    const int a  = blockIdx.y;
    const int b0 = blockIdx.x * 64;
    const int tx = threadIdx.x;
    const int w  = tx >> 6;        // wave 0..3 -> b sub-tile
    const int l  = tx & 63;
    const int li = l & 15;         // A: row(b) / B: col(c) / D: col(c)
    const int kg = l >> 4;         // k group 0..3

    __shared__ float sf0[RANK];
    if (tx < RANK) sf0[tx] = f01t[a * RANK + tx];   // f0t[a][*]
    __syncthreads();

    const int brow = b0 + w * 16 + li;
    const float* f1p = f01t + (size_t)(NPTS + brow) * RANK;

    f32x4 acc[20];
    #pragma unroll
    for (int t = 0; t < 20; ++t) acc[t] = (f32x4){0.f, 0.f, 0.f, 0.f};

    #pragma unroll
    for (int ks = 0; ks < 2; ++ks) {
        const int k0 = ks * 32 + kg * 8;

        // ---- build A fragments: g[j] = f0[a][k0+j] * f1[brow][k0+j] ----
        float4 f1a = *(const float4*)(f1p + k0);
        float4 f1b = *(const float4*)(f1p + k0 + 4);
        float4 f0a = *(const float4*)(&sf0[k0]);
        float4 f0b = *(const float4*)(&sf0[k0 + 4]);

        float g[8];
        g[0] = f1a.x * f0a.x; g[1] = f1a.y * f0a.y;
        g[2] = f1a.z * f0a.z; g[3] = f1a.w * f0a.w;
        g[4] = f1b.x * f0b.x; g[5] = f1b.y * f0b.y;
        g[6] = f1b.z * f0b.z; g[7] = f1b.w * f0b.w;

        bf16x8 a_hi, a_lo;
        #pragma unroll
        for (int j = 0; j < 8; ++j) {
            unsigned short hi = f2bf_rn(g[j]);
            a_hi[j] = (short)hi;
            a_lo[j] = (short)f2bf_rn(g[j] - bf2f(hi));
        }

        // ---- 20 c-tiles: load B (hi/lo), 3 MFMAs each ----
        const unsigned short* bh_base = f2hi + (size_t)li * RANK + k0;
        const unsigned short* bl_base = f2lo + (size_t)li * RANK + k0;
        #pragma unroll
        for (int ct = 0; ct < 20; ++ct) {
            bf16x8 b_hi = *(const bf16x8*)(bh_base + (size_t)ct * 16 * RANK);
            bf16x8 b_lo = *(const bf16x8*)(bl_base + (size_t)ct * 16 * RANK);
            acc[ct] = __builtin_amdgcn_mfma_f32_16x16x32_bf16(a_hi, b_hi, acc[ct], 0, 0, 0);
            acc[ct] = __builtin_amdgcn_mfma_f32_16x16x32_bf16(a_hi, b_lo, acc[ct], 0, 0, 0);
            acc[ct] = __builtin_amdgcn_mfma_f32_16x16x32_bf16(a_lo, b_hi, acc[ct], 0, 0, 0);
        }
    }

    // ---- epilogue: D layout col=lane&15 (c), row=(lane>>4)*4+q (b) ----
    float* obase = out + ((size_t)a * NPTS + (b0 + w * 16 + kg * 4)) * NPTS + li;
    #pragma unroll
    for (int ct = 0; ct < 20; ++ct) {
        #pragma unroll
        for (int q = 0; q < 4; ++q) {
            obase[(size_t)q * NPTS + ct * 16] = acc[ct][q];
        }
    }
}

extern "C" void kernel_launch(void* const* d_in, const int* in_sizes, int n_in,
                              void* d_out, int out_size, void* d_ws, size_t ws_size,
                              hipStream_t stream) {
    const float* xs = (const float*)d_in[0];
    const float* W0 = (const float*)d_in[1];
    const float* b0 = (const float*)d_in[2];
    const float* W1 = (const float*)d_in[3];
    const float* b1 = (const float*)d_in[4];
    const float* W2 = (const float*)d_in[5];
    const float* b2 = (const float*)d_in[6];
    const float* W3 = (const float*)d_in[7];
    const float* b3 = (const float*)d_in[8];

    // workspace layout (total 240 KB):
    //   f01t : float [2][NPTS][RANK]           = 163840 B
    //   f2hi : ushort [NPTS][RANK]             =  40960 B
    //   f2lo : ushort [NPTS][RANK]             =  40960 B
    float* f01t = (float*)d_ws;
    unsigned short* f2hi = (unsigned short*)((char*)d_ws + 2 * NPTS * RANK * 4);
    unsigned short* f2lo = f2hi + NPTS * RANK;
    float* out = (float*)d_out;

    mlp_kernel<<<dim3(DIMS * NPTS), dim3(HID), 0, stream>>>(
        xs, W0, b0, W1, b1, W2, b2, W3, b3, f01t, f2hi, f2lo);

    dim3 grid(NPTS / 64, NPTS);   // (5 b-tiles, 320 a)
    cp_mfma_kernel<<<grid, dim3(256), 0, stream>>>(f01t, f2hi, f2lo, out);
}

// Round 3
// 54.889 us; speedup vs baseline: 1.7607x; 1.7607x over previous
//
#include <hip/hip_runtime.h>
#include <math.h>

#define DIMS 3
#define NPTS 320
#define HID  128
#define RANK 64
#define ROWB 128   // bytes per f2 row = RANK * sizeof(bf16)

typedef __attribute__((ext_vector_type(8))) short  bf16x8;
typedef __attribute__((ext_vector_type(4))) float  f32x4;

// round-to-nearest-even float -> bf16 bits
static __device__ __forceinline__ unsigned short f2bf_rn(float x) {
    union { float f; unsigned int u; } v; v.f = x;
    unsigned int r = v.u + 0x7fffu + ((v.u >> 16) & 1u);
    return (unsigned short)(r >> 16);
}
static __device__ __forceinline__ float bf2f(unsigned short h) {
    union { unsigned int u; float f; } v; v.u = ((unsigned int)h) << 16;
    return v.f;
}

// ---------------- Phase 1: per-dim MLP -> transposed factor tables ----------
// f0t[a][r], f1t[b][r] fp32 in f01t[2][NPTS][RANK];
// f2t split to bf16 hi/lo: f2hi[c][r], f2lo[c][r].
__global__ __launch_bounds__(HID)
void mlp_kernel(const float* __restrict__ xs,
                const float* __restrict__ W0, const float* __restrict__ b0,
                const float* __restrict__ W1, const float* __restrict__ b1,
                const float* __restrict__ W2, const float* __restrict__ b2,
                const float* __restrict__ W3, const float* __restrict__ b3,
                float* __restrict__ f01t,
                unsigned short* __restrict__ f2hi,
                unsigned short* __restrict__ f2lo) {
    int blk = blockIdx.x;
    int d = blk / NPTS, n = blk % NPTS;
    int j = threadIdx.x;

    __shared__ float ha[HID];
    __shared__ float hb[HID];

    float x = xs[d * NPTS + n];

    ha[j] = tanhf(fmaf(x, W0[d * HID + j], b0[d * HID + j]));
    __syncthreads();

    {
        float acc = b1[d * HID + j];
        const float* w = W1 + d * HID * HID + j;
        #pragma unroll 8
        for (int k = 0; k < HID; ++k) acc = fmaf(ha[k], w[k * HID], acc);
        hb[j] = tanhf(acc);
    }
    __syncthreads();

    {
        float acc = b2[d * HID + j];
        const float* w = W2 + d * HID * HID + j;
        #pragma unroll 8
        for (int k = 0; k < HID; ++k) acc = fmaf(hb[k], w[k * HID], acc);
        ha[j] = tanhf(acc);
    }
    __syncthreads();

    if (j < RANK) {
        float acc = b3[d * RANK + j];
        const float* w = W3 + d * HID * RANK + j;
        #pragma unroll 8
        for (int k = 0; k < HID; ++k) acc = fmaf(ha[k], w[k * RANK], acc);

        if (d == 0) {
            f01t[n * RANK + j] = acc;                    // f0t[a][r]
        } else if (d == 1) {
            f01t[(NPTS + n) * RANK + j] = acc;           // f1t[b][r]
        } else {
            unsigned short hi = f2bf_rn(acc);
            f2hi[n * RANK + j] = hi;
            f2lo[n * RANK + j] = f2bf_rn(acc - bf2f(hi));
        }
    }
}

// ---------------- Phase 2: CP reconstruction via bf16 MFMA (hi/lo split) ----
// out[a,b,c] = sum_r (f0[a,r]*f1[b,r]) * f2[c,r]
// Block: one a, 64-wide b tile (4 waves x 16 rows), full c=320 (20 tiles).
// f2hi/f2lo staged in LDS (80 KB) with XOR swizzle byte^=((row&7)<<4) so
// ds_read_b128 fragment reads are bank-conflict-free. A frag built in-register.
__global__ __launch_bounds__(256)
void cp_mfma_kernel(const float* __restrict__ f01t,
                    const unsigned short* __restrict__ f2hi,
                    const unsigned short* __restrict__ f2lo,
                    float* __restrict__ out) {
    const int a  = blockIdx.y;
    const int b0 = blockIdx.x * 64;
    const int tx = threadIdx.x;
    const int w  = tx >> 6;        // wave 0..3 -> b sub-tile
    const int l  = tx & 63;
    const int li = l & 15;         // A: row(b) / B: row(c) / D: col(c)
    const int kg = l >> 4;         // k group 0..3

    __shared__ char  sB[2][NPTS * ROWB];   // 80 KB: [hi/lo][c][128B], swizzled
    __shared__ float sf0[RANK];

    // ---- stage f2 tables: coalesced float4 reads, swizzled ds_write_b128 ----
    {
        #pragma unroll
        for (int t = 0; t < 10; ++t) {
            int idx   = tx + t * 256;             // float4 index, 2560/table
            int row   = idx >> 3;                 // c row (16B granules: 8/row)
            int inner = (idx & 7) << 4;           // byte offset within row
            int dst   = row * ROWB + (inner ^ ((row & 7) << 4));
            *(float4*)(&sB[0][dst]) = ((const float4*)f2hi)[idx];
            *(float4*)(&sB[1][dst]) = ((const float4*)f2lo)[idx];
        }
        if (tx < RANK) sf0[tx] = f01t[a * RANK + tx];
    }
    __syncthreads();

    const int brow = b0 + w * 16 + li;
    const float* f1p = f01t + (size_t)(NPTS + brow) * RANK;

    f32x4 acc[20];
    #pragma unroll
    for (int t = 0; t < 20; ++t) acc[t] = (f32x4){0.f, 0.f, 0.f, 0.f};

    #pragma unroll
    for (int ks = 0; ks < 2; ++ks) {
        const int k0 = ks * 32 + kg * 8;

        // ---- build A fragments: g[j] = f0[a][k0+j] * f1[brow][k0+j] ----
        float4 f1a = *(const float4*)(f1p + k0);
        float4 f1b = *(const float4*)(f1p + k0 + 4);
        float4 f0a = *(const float4*)(&sf0[k0]);
        float4 f0b = *(const float4*)(&sf0[k0 + 4]);

        float g[8];
        g[0] = f1a.x * f0a.x; g[1] = f1a.y * f0a.y;
        g[2] = f1a.z * f0a.z; g[3] = f1a.w * f0a.w;
        g[4] = f1b.x * f0b.x; g[5] = f1b.y * f0b.y;
        g[6] = f1b.z * f0b.z; g[7] = f1b.w * f0b.w;

        bf16x8 a_hi, a_lo;
        #pragma unroll
        for (int j = 0; j < 8; ++j) {
            unsigned short hi = f2bf_rn(g[j]);
            a_hi[j] = (short)hi;
            a_lo[j] = (short)f2bf_rn(g[j] - bf2f(hi));
        }

        // ---- 20 c-tiles: swizzled LDS B reads (conflict-free), 3 MFMAs ----
        // lane byte offset within a 16-row stripe:
        const int binner = li * ROWB + (((ks * 64 + kg * 16) ^ ((li & 7) << 4)));
        #pragma unroll
        for (int ct = 0; ct < 20; ++ct) {
            bf16x8 b_hi = *(const bf16x8*)(&sB[0][ct * 16 * ROWB + binner]);
            bf16x8 b_lo = *(const bf16x8*)(&sB[1][ct * 16 * ROWB + binner]);
            acc[ct] = __builtin_amdgcn_mfma_f32_16x16x32_bf16(a_hi, b_hi, acc[ct], 0, 0, 0);
            acc[ct] = __builtin_amdgcn_mfma_f32_16x16x32_bf16(a_hi, b_lo, acc[ct], 0, 0, 0);
            acc[ct] = __builtin_amdgcn_mfma_f32_16x16x32_bf16(a_lo, b_hi, acc[ct], 0, 0, 0);
        }
    }

    // ---- epilogue: D layout col=lane&15 (c), row=(lane>>4)*4+q (b) ----
    float* obase = out + ((size_t)a * NPTS + (b0 + w * 16 + kg * 4)) * NPTS + li;
    #pragma unroll
    for (int ct = 0; ct < 20; ++ct) {
        #pragma unroll
        for (int q = 0; q < 4; ++q) {
            obase[(size_t)q * NPTS + ct * 16] = acc[ct][q];
        }
    }
}

extern "C" void kernel_launch(void* const* d_in, const int* in_sizes, int n_in,
                              void* d_out, int out_size, void* d_ws, size_t ws_size,
                              hipStream_t stream) {
    const float* xs = (const float*)d_in[0];
    const float* W0 = (const float*)d_in[1];
    const float* b0 = (const float*)d_in[2];
    const float* W1 = (const float*)d_in[3];
    const float* b1 = (const float*)d_in[4];
    const float* W2 = (const float*)d_in[5];
    const float* b2 = (const float*)d_in[6];
    const float* W3 = (const float*)d_in[7];
    const float* b3 = (const float*)d_in[8];

    // workspace layout (total 240 KB):
    //   f01t : float [2][NPTS][RANK]           = 163840 B
    //   f2hi : ushort [NPTS][RANK]             =  40960 B
    //   f2lo : ushort [NPTS][RANK]             =  40960 B
    float* f01t = (float*)d_ws;
    unsigned short* f2hi = (unsigned short*)((char*)d_ws + 2 * NPTS * RANK * 4);
    unsigned short* f2lo = f2hi + NPTS * RANK;
    float* out = (float*)d_out;

    mlp_kernel<<<dim3(DIMS * NPTS), dim3(HID), 0, stream>>>(
        xs, W0, b0, W1, b1, W2, b2, W3, b3, f01t, f2hi, f2lo);

    dim3 grid(NPTS / 64, NPTS);   // (5 b-tiles, 320 a)
    cp_mfma_kernel<<<grid, dim3(256), 0, stream>>>(f01t, f2hi, f2lo, out);
}

// Round 4
// 50.545 us; speedup vs baseline: 1.9120x; 1.0859x over previous
//
#include <hip/hip_runtime.h>
#include <math.h>

#define DIMS 3
#define NPTS 320
#define HID  128
#define RANK 64
#define ROWB 128   // bytes per f2 row = RANK * sizeof(bf16)
#define NBLK 512   // persistent blocks: 2 per CU (80 KB LDS each)
#define NTIL 1600  // (NPTS) a-values x (NPTS/64) b-tiles

typedef __attribute__((ext_vector_type(8))) short  bf16x8;
typedef __attribute__((ext_vector_type(4))) float  f32x4;

// round-to-nearest-even float -> bf16 bits
static __device__ __forceinline__ unsigned short f2bf_rn(float x) {
    union { float f; unsigned int u; } v; v.f = x;
    unsigned int r = v.u + 0x7fffu + ((v.u >> 16) & 1u);
    return (unsigned short)(r >> 16);
}
static __device__ __forceinline__ float bf2f(unsigned short h) {
    union { unsigned int u; float f; } v; v.u = ((unsigned int)h) << 16;
    return v.f;
}

// ---------------- Phase 1: per-dim MLP -> transposed factor tables ----------
__global__ __launch_bounds__(HID)
void mlp_kernel(const float* __restrict__ xs,
                const float* __restrict__ W0, const float* __restrict__ b0,
                const float* __restrict__ W1, const float* __restrict__ b1,
                const float* __restrict__ W2, const float* __restrict__ b2,
                const float* __restrict__ W3, const float* __restrict__ b3,
                float* __restrict__ f01t,
                unsigned short* __restrict__ f2hi,
                unsigned short* __restrict__ f2lo) {
    int blk = blockIdx.x;
    int d = blk / NPTS, n = blk % NPTS;
    int j = threadIdx.x;

    __shared__ float ha[HID];
    __shared__ float hb[HID];

    float x = xs[d * NPTS + n];

    ha[j] = tanhf(fmaf(x, W0[d * HID + j], b0[d * HID + j]));
    __syncthreads();

    {
        float acc = b1[d * HID + j];
        const float* w = W1 + d * HID * HID + j;
        #pragma unroll 8
        for (int k = 0; k < HID; ++k) acc = fmaf(ha[k], w[k * HID], acc);
        hb[j] = tanhf(acc);
    }
    __syncthreads();

    {
        float acc = b2[d * HID + j];
        const float* w = W2 + d * HID * HID + j;
        #pragma unroll 8
        for (int k = 0; k < HID; ++k) acc = fmaf(hb[k], w[k * HID], acc);
        ha[j] = tanhf(acc);
    }
    __syncthreads();

    if (j < RANK) {
        float acc = b3[d * RANK + j];
        const float* w = W3 + d * HID * RANK + j;
        #pragma unroll 8
        for (int k = 0; k < HID; ++k) acc = fmaf(ha[k], w[k * RANK], acc);

        if (d == 0) {
            f01t[n * RANK + j] = acc;                    // f0t[a][r]
        } else if (d == 1) {
            f01t[(NPTS + n) * RANK + j] = acc;           // f1t[b][r]
        } else {
            unsigned short hi = f2bf_rn(acc);
            f2hi[n * RANK + j] = hi;
            f2lo[n * RANK + j] = f2bf_rn(acc - bf2f(hi));
        }
    }
}

// ---------------- Phase 2: persistent-block CP reconstruction ----------------
// out[a,b,c] = sum_r (f0[a,r]*f1[b,r]) * f2[c,r]
// 512 persistent blocks (2/CU). Each stages f2hi/f2lo in LDS ONCE (swizzled),
// then loops over (a, b-tile) assignments with no barriers: f0/f1 rows read
// per-lane from the hot L1/L2-resident tables, stores overlap next tile's
// compute via wave pipelining.
__global__ __launch_bounds__(256)
void cp_mfma_kernel(const float* __restrict__ f01t,
                    const unsigned short* __restrict__ f2hi,
                    const unsigned short* __restrict__ f2lo,
                    float* __restrict__ out) {
    const int tx = threadIdx.x;
    const int w  = tx >> 6;        // wave 0..3 -> b sub-tile
    const int l  = tx & 63;
    const int li = l & 15;         // A: row(b) / B: row(c) / D: col(c)
    const int kg = l >> 4;         // k group 0..3

    __shared__ char sB[2][NPTS * ROWB];   // 80 KB, swizzled byte^=((row&7)<<4)

    // ---- stage f2 tables once: coalesced reads, swizzled ds_write_b128 ----
    #pragma unroll
    for (int t = 0; t < 10; ++t) {
        int idx   = tx + t * 256;             // float4 index, 2560/table
        int row   = idx >> 3;                 // c row (8 granules of 16B/row)
        int inner = (idx & 7) << 4;
        int dst   = row * ROWB + (inner ^ ((row & 7) << 4));
        *(float4*)(&sB[0][dst]) = ((const float4*)f2hi)[idx];
        *(float4*)(&sB[1][dst]) = ((const float4*)f2lo)[idx];
    }
    __syncthreads();

    for (int t = blockIdx.x; t < NTIL; t += NBLK) {
        const int a  = t / 5;
        const int b0 = (t - a * 5) * 64;
        const int brow = b0 + w * 16 + li;
        const float* f0p = f01t + (size_t)a * RANK;
        const float* f1p = f01t + (size_t)(NPTS + brow) * RANK;

        f32x4 acc[20];
        #pragma unroll
        for (int i = 0; i < 20; ++i) acc[i] = (f32x4){0.f, 0.f, 0.f, 0.f};

        #pragma unroll
        for (int ks = 0; ks < 2; ++ks) {
            const int k0 = ks * 32 + kg * 8;

            float4 f0a = *(const float4*)(f0p + k0);
            float4 f0b = *(const float4*)(f0p + k0 + 4);
            float4 f1a = *(const float4*)(f1p + k0);
            float4 f1b = *(const float4*)(f1p + k0 + 4);

            float g[8];
            g[0] = f1a.x * f0a.x; g[1] = f1a.y * f0a.y;
            g[2] = f1a.z * f0a.z; g[3] = f1a.w * f0a.w;
            g[4] = f1b.x * f0b.x; g[5] = f1b.y * f0b.y;
            g[6] = f1b.z * f0b.z; g[7] = f1b.w * f0b.w;

            bf16x8 a_hi, a_lo;
            #pragma unroll
            for (int j = 0; j < 8; ++j) {
                unsigned short hi = f2bf_rn(g[j]);
                a_hi[j] = (short)hi;
                a_lo[j] = (short)f2bf_rn(g[j] - bf2f(hi));
            }

            const int binner = li * ROWB + ((ks * 64 + kg * 16) ^ ((li & 7) << 4));
            #pragma unroll
            for (int ct = 0; ct < 20; ++ct) {
                bf16x8 b_hi = *(const bf16x8*)(&sB[0][ct * 16 * ROWB + binner]);
                bf16x8 b_lo = *(const bf16x8*)(&sB[1][ct * 16 * ROWB + binner]);
                acc[ct] = __builtin_amdgcn_mfma_f32_16x16x32_bf16(a_hi, b_hi, acc[ct], 0, 0, 0);
                acc[ct] = __builtin_amdgcn_mfma_f32_16x16x32_bf16(a_hi, b_lo, acc[ct], 0, 0, 0);
                acc[ct] = __builtin_amdgcn_mfma_f32_16x16x32_bf16(a_lo, b_hi, acc[ct], 0, 0, 0);
            }
        }

        // epilogue: D layout col=lane&15 (c), row=(lane>>4)*4+q (b)
        float* obase = out + ((size_t)a * NPTS + (b0 + w * 16 + kg * 4)) * NPTS + li;
        #pragma unroll
        for (int ct = 0; ct < 20; ++ct) {
            #pragma unroll
            for (int q = 0; q < 4; ++q) {
                obase[(size_t)q * NPTS + ct * 16] = acc[ct][q];
            }
        }
    }
}

extern "C" void kernel_launch(void* const* d_in, const int* in_sizes, int n_in,
                              void* d_out, int out_size, void* d_ws, size_t ws_size,
                              hipStream_t stream) {
    const float* xs = (const float*)d_in[0];
    const float* W0 = (const float*)d_in[1];
    const float* b0 = (const float*)d_in[2];
    const float* W1 = (const float*)d_in[3];
    const float* b1 = (const float*)d_in[4];
    const float* W2 = (const float*)d_in[5];
    const float* b2 = (const float*)d_in[6];
    const float* W3 = (const float*)d_in[7];
    const float* b3 = (const float*)d_in[8];

    // workspace: f01t float[2][NPTS][RANK] | f2hi ushort[NPTS][RANK] | f2lo same
    float* f01t = (float*)d_ws;
    unsigned short* f2hi = (unsigned short*)((char*)d_ws + 2 * NPTS * RANK * 4);
    unsigned short* f2lo = f2hi + NPTS * RANK;
    float* out = (float*)d_out;

    mlp_kernel<<<dim3(DIMS * NPTS), dim3(HID), 0, stream>>>(
        xs, W0, b0, W1, b1, W2, b2, W3, b3, f01t, f2hi, f2lo);

    cp_mfma_kernel<<<dim3(NBLK), dim3(256), 0, stream>>>(f01t, f2hi, f2lo, out);
}